// Round 3
// baseline (8626.380 us; speedup 1.0000x reference)
//
#include <hip/hip_runtime.h>
#include <hip/hip_bf16.h>

// ---------------------------------------------------------------------------
// KimiDeltaAttention — round 3: latency-optimized scan (in-lane columns).
// Pipeline:
//  1) gemm_tile z=3 : h@{Wq,Wk,Wv} -> qb,kb,vb            [4096x2048 each]
//  2) gemm_tile z=2 : h@{Wfa,Wga}  -> tmpf,tmpg           [4096x128]
//  3) gemm_tile z=2 : {tmpf@Wfb, tmpg@Wgb} -> gb, gateb   [4096x2048]
//  4) gemm_n16      : h@Wb -> betab                       [4096x16]
//  5) conv_silu     : depthwise causal K=4 conv + SiLU, in-place on qb,kb,vb
//  6) prep_qkg      : l2norm(q)*D^-1/2, l2norm(k), g -> exp(g) (in-place)
//  7) kda_scan      : gated delta rule; thread = one S-column (in-lane dots)
//  8) norm_gate     : RMSNorm(o)*norm_w*sigmoid(gate)     (in-place on ob)
//  9) gemm_tile     : ob@Wo -> d_out (f32)
// ---------------------------------------------------------------------------

// ---------------- tiled f32 GEMM: C[M,N] = A[M,K] @ B[K,N] ------------------
__global__ __launch_bounds__(256) void gemm_tile(
    const float* __restrict__ A0, const float* __restrict__ A1, const float* __restrict__ A2,
    const float* __restrict__ B0, const float* __restrict__ B1, const float* __restrict__ B2,
    float* __restrict__ C0, float* __restrict__ C1, float* __restrict__ C2,
    int M, int N, int Kd)
{
    const int z = blockIdx.z;
    const float* A = (z == 0) ? A0 : (z == 1) ? A1 : A2;
    const float* B = (z == 0) ? B0 : (z == 1) ? B1 : B2;
    float* C       = (z == 0) ? C0 : (z == 1) ? C1 : C2;

    __shared__ float As[8][128];   // As[k][m]
    __shared__ float Bs[8][128];   // Bs[k][n]

    const int tid  = threadIdx.x;
    const int bm   = blockIdx.x * 128;
    const int bn   = blockIdx.y * 128;
    const int arow = tid >> 1;             // 0..127
    const int acol = (tid & 1) << 2;       // 0 or 4
    const int brow = tid >> 5;             // 0..7
    const int bcol = (tid & 31) << 2;      // 0..124
    const int ty   = tid >> 4;             // 0..15
    const int tx   = tid & 15;             // 0..15

    float acc[8][8];
#pragma unroll
    for (int i = 0; i < 8; ++i)
#pragma unroll
        for (int j = 0; j < 8; ++j) acc[i][j] = 0.f;

    const float* Ap = A + (size_t)(bm + arow) * Kd + acol;
    const float* Bp = B + (size_t)brow * N + (bn + bcol);

    for (int k0 = 0; k0 < Kd; k0 += 8) {
        float4 av = *(const float4*)(Ap + k0);
        float4 bv = *(const float4*)(Bp + (size_t)k0 * N);
        As[acol + 0][arow] = av.x;
        As[acol + 1][arow] = av.y;
        As[acol + 2][arow] = av.z;
        As[acol + 3][arow] = av.w;
        *(float4*)&Bs[brow][bcol] = bv;
        __syncthreads();
#pragma unroll
        for (int k = 0; k < 8; ++k) {
            float4 a0 = *(const float4*)&As[k][ty * 4];
            float4 a1 = *(const float4*)&As[k][64 + ty * 4];
            float4 b0 = *(const float4*)&Bs[k][tx * 4];
            float4 b1 = *(const float4*)&Bs[k][64 + tx * 4];
            float aa[8] = {a0.x, a0.y, a0.z, a0.w, a1.x, a1.y, a1.z, a1.w};
            float bb[8] = {b0.x, b0.y, b0.z, b0.w, b1.x, b1.y, b1.z, b1.w};
#pragma unroll
            for (int i = 0; i < 8; ++i)
#pragma unroll
                for (int j = 0; j < 8; ++j)
                    acc[i][j] = fmaf(aa[i], bb[j], acc[i][j]);
        }
        __syncthreads();
    }

#pragma unroll
    for (int i = 0; i < 8; ++i) {
        int r = bm + ((i >> 2) << 6) + ty * 4 + (i & 3);
#pragma unroll
        for (int jg = 0; jg < 2; ++jg) {
            int c = bn + (jg << 6) + tx * 4;
            float4 v = make_float4(acc[i][jg * 4 + 0], acc[i][jg * 4 + 1],
                                   acc[i][jg * 4 + 2], acc[i][jg * 4 + 3]);
            *(float4*)(C + (size_t)r * N + c) = v;
        }
    }
}

// ------------------- small-N GEMM for beta: N = 16 -------------------------
__global__ __launch_bounds__(256) void gemm_n16(
    const float* __restrict__ A, const float* __restrict__ B,
    float* __restrict__ C, int M, int Kd)
{
    const int tid  = threadIdx.x;
    const int n    = tid & 15;
    const int mloc = tid >> 4;  // 0..15
    const int m    = blockIdx.x * 16 + mloc;
    const float* a  = A + (size_t)m * Kd;
    const float* bn = B + n;
    float acc = 0.f;
#pragma unroll 4
    for (int k0 = 0; k0 < Kd; k0 += 8) {
        float4 a0 = *(const float4*)(a + k0);
        float4 a1 = *(const float4*)(a + k0 + 4);
        acc = fmaf(a0.x, bn[(size_t)(k0 + 0) * 16], acc);
        acc = fmaf(a0.y, bn[(size_t)(k0 + 1) * 16], acc);
        acc = fmaf(a0.z, bn[(size_t)(k0 + 2) * 16], acc);
        acc = fmaf(a0.w, bn[(size_t)(k0 + 3) * 16], acc);
        acc = fmaf(a1.x, bn[(size_t)(k0 + 4) * 16], acc);
        acc = fmaf(a1.y, bn[(size_t)(k0 + 5) * 16], acc);
        acc = fmaf(a1.z, bn[(size_t)(k0 + 6) * 16], acc);
        acc = fmaf(a1.w, bn[(size_t)(k0 + 7) * 16], acc);
    }
    C[(size_t)m * 16 + n] = acc;
}

// --------------- depthwise causal conv (K=4) + SiLU, in-place ---------------
__global__ __launch_bounds__(256) void conv_silu(
    float* __restrict__ q, float* __restrict__ k, float* __restrict__ v,
    const float* __restrict__ wq, const float* __restrict__ wk,
    const float* __restrict__ wv)
{
    constexpr int T = 2048, C = 2048;
    const int gid   = blockIdx.x * 256 + threadIdx.x;  // 0..12287
    const int which = gid >> 12;                        // tensor 0,1,2
    const int rem   = gid & 4095;
    const int b     = rem >> 11;
    const int c     = rem & 2047;
    float* x        = (which == 0) ? q : (which == 1) ? k : v;
    const float* w  = (which == 0) ? wq : (which == 1) ? wk : wv;

    const float w0 = w[c * 4 + 0], w1 = w[c * 4 + 1];
    const float w2 = w[c * 4 + 2], w3 = w[c * 4 + 3];
    float* p = x + (size_t)b * T * C + c;
    float xm3 = 0.f, xm2 = 0.f, xm1 = 0.f;

    for (int t0 = 0; t0 < T; t0 += 16) {
        float xt[16], yo[16];
#pragma unroll
        for (int j = 0; j < 16; ++j) xt[j] = p[(size_t)(t0 + j) * C];
#pragma unroll
        for (int j = 0; j < 16; ++j) {
            float y = fmaf(xm3, w0, fmaf(xm2, w1, fmaf(xm1, w2, xt[j] * w3)));
            yo[j] = y / (1.f + __expf(-y));   // SiLU
            xm3 = xm2; xm2 = xm1; xm1 = xt[j];
        }
#pragma unroll
        for (int j = 0; j < 16; ++j) p[(size_t)(t0 + j) * C] = yo[j];
    }
}

// ------ prep: l2norm(q)*D^-0.5, l2norm(k), g -> exp(-exp(A_log)*softplus) ---
__global__ __launch_bounds__(256) void prep_qkg(
    float* __restrict__ Qb, float* __restrict__ Kb, float* __restrict__ Gb,
    const float* __restrict__ A_log, const float* __restrict__ dt_bias,
    int rows)
{
    const int wave = threadIdx.x >> 6;
    const int lane = threadIdx.x & 63;
    const int row  = blockIdx.x * 4 + wave;
    if (row >= rows) return;
    const int hh = row & 15;             // row = ((b*T+t)*16 + h)
    const size_t base = (size_t)row * 128;

    float q0 = Qb[base + lane], q1 = Qb[base + 64 + lane];
    float k0 = Kb[base + lane], k1 = Kb[base + 64 + lane];
    float sq = q0 * q0 + q1 * q1;
    float sk = k0 * k0 + k1 * k1;
#pragma unroll
    for (int off = 32; off >= 1; off >>= 1) {
        sq += __shfl_xor(sq, off);
        sk += __shfl_xor(sk, off);
    }
    const float qs = rsqrtf(sq + 1e-6f) * 0.08838834764831845f;  // * D^-1/2
    const float ks = rsqrtf(sk + 1e-6f);
    Qb[base + lane] = q0 * qs; Qb[base + 64 + lane] = q1 * qs;
    Kb[base + lane] = k0 * ks; Kb[base + 64 + lane] = k1 * ks;

    const float a = __expf(A_log[hh]);
    float x0 = Gb[base + lane]      + dt_bias[hh * 128 + lane];
    float x1 = Gb[base + 64 + lane] + dt_bias[hh * 128 + 64 + lane];
    float sp0 = (x0 > 20.f) ? x0 : log1pf(__expf(x0));
    float sp1 = (x1 > 20.f) ? x1 : log1pf(__expf(x1));
    Gb[base + lane]      = __expf(-a * sp0);   // store exp(g)
    Gb[base + 64 + lane] = __expf(-a * sp1);
}

// --------------------- gated delta-rule sequential scan ---------------------
// block = (b,h); 128 threads; thread owns FULL S column dv=tid (128 f32 regs).
// kS / delta / o are in-lane dot products — NO cross-lane reduction, ONE
// barrier per step. k/eg/q staged in double-buffered LDS (broadcast float4
// reads); v/beta are per-lane registers. Full-step-deep global prefetch.
__global__ __launch_bounds__(128) void kda_scan(
    const float* __restrict__ Q, const float* __restrict__ Kk,
    const float* __restrict__ V, const float* __restrict__ EG,
    const float* __restrict__ Braw, float* __restrict__ O)
{
    constexpr int T = 2048, H = 16, D = 128, HD = H * D;
    const int bh  = blockIdx.x;
    const int b   = bh >> 4;
    const int hh  = bh & 15;
    const int tid = threadIdx.x;   // dv = owned value-column

    __shared__ __align__(16) float k_s[2][D];
    __shared__ __align__(16) float e_s[2][D];
    __shared__ __align__(16) float q_s[2][D];

    float s[D];
#pragma unroll
    for (int i = 0; i < D; ++i) s[i] = 0.f;

    const size_t base = ((size_t)b * T * H + hh) * D;
    const float* qp = Q + base;
    const float* kp = Kk + base;
    const float* vp = V + base;
    const float* ep = EG + base;
    const float* bp = Braw + (size_t)b * T * H + hh;
    float* op = O + base;

    // preload t = 0
    k_s[0][tid] = kp[tid];
    e_s[0][tid] = ep[tid];
    q_s[0][tid] = qp[tid];
    float rv = vp[tid];
    float rb = bp[0];
    __syncthreads();

    for (int t = 0; t < T; ++t) {
        const int cur  = t & 1;
        const bool more = (t + 1 < T);
        float pk = 0.f, pe = 0.f, pq = 0.f, pv = 0.f, pb = 0.f;
        if (more) {   // prefetch t+1 (hidden under this step's compute)
            const size_t off = (size_t)(t + 1) * HD;
            pk = kp[off + tid]; pe = ep[off + tid]; pq = qp[off + tid];
            pv = vp[off + tid]; pb = bp[(size_t)(t + 1) * H];
        }
        const float beta = 1.f / (1.f + __expf(-rb));

        // pass 1: decay state + in-lane k^T S (4 accumulators for ILP)
        float a0 = 0.f, a1 = 0.f, a2 = 0.f, a3 = 0.f;
#pragma unroll
        for (int i = 0; i < D / 4; ++i) {
            const float4 e4 = *(const float4*)&e_s[cur][4 * i];
            const float4 k4 = *(const float4*)&k_s[cur][4 * i];
            float s0 = s[4 * i + 0] * e4.x;
            float s1 = s[4 * i + 1] * e4.y;
            float s2 = s[4 * i + 2] * e4.z;
            float s3 = s[4 * i + 3] * e4.w;
            s[4 * i + 0] = s0; s[4 * i + 1] = s1;
            s[4 * i + 2] = s2; s[4 * i + 3] = s3;
            a0 = fmaf(k4.x, s0, a0); a1 = fmaf(k4.y, s1, a1);
            a2 = fmaf(k4.z, s2, a2); a3 = fmaf(k4.w, s3, a3);
        }
        const float kS    = (a0 + a1) + (a2 + a3);
        const float delta = beta * (rv - kS);

        // pass 2: rank-1 update + in-lane q^T S
        float o0 = 0.f, o1 = 0.f, o2 = 0.f, o3 = 0.f;
#pragma unroll
        for (int i = 0; i < D / 4; ++i) {
            const float4 k4 = *(const float4*)&k_s[cur][4 * i];
            const float4 q4 = *(const float4*)&q_s[cur][4 * i];
            float s0 = fmaf(k4.x, delta, s[4 * i + 0]);
            float s1 = fmaf(k4.y, delta, s[4 * i + 1]);
            float s2 = fmaf(k4.z, delta, s[4 * i + 2]);
            float s3 = fmaf(k4.w, delta, s[4 * i + 3]);
            s[4 * i + 0] = s0; s[4 * i + 1] = s1;
            s[4 * i + 2] = s2; s[4 * i + 3] = s3;
            o0 = fmaf(q4.x, s0, o0); o1 = fmaf(q4.y, s1, o1);
            o2 = fmaf(q4.z, s2, o2); o3 = fmaf(q4.w, s3, o3);
        }
        op[(size_t)t * HD + tid] = (o0 + o1) + (o2 + o3);

        if (more) {   // stage t+1 into the other buffer
            const int nxt = cur ^ 1;
            k_s[nxt][tid] = pk;
            e_s[nxt][tid] = pe;
            q_s[nxt][tid] = pq;
            rv = pv; rb = pb;
        }
        __syncthreads();   // single barrier: write(nxt) <-> read(nxt) fence
    }
}

// --------------- gated RMSNorm: o = rms(o)*norm_w*sigmoid(gate) -------------
__global__ __launch_bounds__(256) void norm_gate(
    float* __restrict__ O, const float* __restrict__ Gate,
    const float* __restrict__ norm_w, int rows)
{
    const int wave = threadIdx.x >> 6;
    const int lane = threadIdx.x & 63;
    const int row  = blockIdx.x * 4 + wave;
    if (row >= rows) return;
    const size_t base = (size_t)row * 128;

    float o0 = O[base + lane], o1 = O[base + 64 + lane];
    float ss = o0 * o0 + o1 * o1;
#pragma unroll
    for (int off = 32; off >= 1; off >>= 1) ss += __shfl_xor(ss, off);
    const float scale = rsqrtf(ss * (1.f / 128.f) + 1e-6f);

    const float g0 = Gate[base + lane], g1 = Gate[base + 64 + lane];
    o0 = o0 * scale * norm_w[lane]      * (1.f / (1.f + __expf(-g0)));
    o1 = o1 * scale * norm_w[64 + lane] * (1.f / (1.f + __expf(-g1)));
    O[base + lane] = o0;
    O[base + 64 + lane] = o1;
}

// ---------------------------------------------------------------------------
extern "C" void kernel_launch(void* const* d_in, const int* in_sizes, int n_in,
                              void* d_out, int out_size, void* d_ws, size_t ws_size,
                              hipStream_t stream)
{
    const float* h    = (const float*)d_in[0];
    const float* Wq   = (const float*)d_in[1];
    const float* Wk   = (const float*)d_in[2];
    const float* Wv   = (const float*)d_in[3];
    const float* cwq  = (const float*)d_in[4];
    const float* cwk  = (const float*)d_in[5];
    const float* cwv  = (const float*)d_in[6];
    const float* A_log= (const float*)d_in[7];
    const float* dtb  = (const float*)d_in[8];
    const float* Wfa  = (const float*)d_in[9];
    const float* Wfb  = (const float*)d_in[10];
    const float* Wb   = (const float*)d_in[11];
    const float* Wga  = (const float*)d_in[12];
    const float* Wgb  = (const float*)d_in[13];
    const float* nw   = (const float*)d_in[14];
    const float* Wo   = (const float*)d_in[15];
    float* out = (float*)d_out;

    const int M = 4096, HID = 2048;
    const size_t big = (size_t)M * HID;
    float* ws    = (float*)d_ws;
    float* qb    = ws;
    float* kb    = qb + big;
    float* vb    = kb + big;
    float* gb    = vb + big;
    float* gateb = gb + big;
    float* ob    = gateb + big;
    float* tmpf  = ob + big;
    float* tmpg  = tmpf + (size_t)M * 128;
    float* betab = tmpg + (size_t)M * 128;

    dim3 blk(256);

    // 1) q/k/v projections (batched, shared A tiles through L2)
    gemm_tile<<<dim3(32, 16, 3), blk, 0, stream>>>(
        h, h, h, Wq, Wk, Wv, qb, kb, vb, M, HID, HID);

    // 2) low-rank stage 1: h@Wfa, h@Wga  (N=128)
    gemm_tile<<<dim3(32, 1, 2), blk, 0, stream>>>(
        h, h, h, Wfa, Wga, Wga, tmpf, tmpg, tmpg, M, 128, HID);

    // 3) low-rank stage 2: tmpf@Wfb -> gb, tmpg@Wgb -> gateb
    gemm_tile<<<dim3(32, 16, 2), blk, 0, stream>>>(
        tmpf, tmpg, tmpg, Wfb, Wgb, Wgb, gb, gateb, gateb, M, HID, 128);

    // 4) beta raw: h@Wb
    gemm_n16<<<dim3(M / 16), blk, 0, stream>>>(h, Wb, betab, M, HID);

    // 5) causal conv + SiLU (in-place on qb/kb/vb)
    conv_silu<<<dim3(48), blk, 0, stream>>>(qb, kb, vb, cwq, cwk, cwv);

    // 6) l2norm q/k, g -> exp(g) (in-place)
    prep_qkg<<<dim3(16384), blk, 0, stream>>>(qb, kb, gb, A_log, dtb, M * 16);

    // 7) gated delta-rule scan (128 threads: one full S-column per lane)
    kda_scan<<<dim3(32), dim3(128), 0, stream>>>(qb, kb, vb, gb, betab, ob);

    // 8) gated RMSNorm (in-place on ob)
    norm_gate<<<dim3(16384), blk, 0, stream>>>(ob, gateb, nw, M * 16);

    // 9) output projection -> f32
    gemm_tile<<<dim3(32, 16, 1), blk, 0, stream>>>(
        ob, ob, ob, Wo, Wo, Wo, out, out, out, M, HID, HID);
}

// Round 4
// 2629.670 us; speedup vs baseline: 3.2804x; 3.2804x over previous
//
#include <hip/hip_runtime.h>
#include <hip/hip_bf16.h>

// ---------------------------------------------------------------------------
// KimiDeltaAttention — round 4.
//  * q/k/v and Wo projections: bf16 MFMA GEMM (16x16x32, 128^2 tile, BK=64,
//    XOR-swizzled LDS). Weights transpose-cast to [N,K] bf16 on device.
//  * g/gate low-rank path stays f32 (decay exp is error-amplifying).
//  * scan: 256 blocks (b,h,vgroup) x 1 wave, lane=(col,k-quarter), s[32]/lane,
//    quad-shuffle reductions, 2-deep prefetch, zero barriers.
// ---------------------------------------------------------------------------

using short8 = __attribute__((ext_vector_type(8))) short;
using f32x4  = __attribute__((ext_vector_type(4))) float;

static __device__ __forceinline__ ushort f2bf(float f) {
    __hip_bfloat16 h = __float2bfloat16(f);
    return *reinterpret_cast<ushort*>(&h);
}

// ----------------------- row-major f32 -> bf16 cast -------------------------
__global__ __launch_bounds__(256) void cast_bf16(const float* __restrict__ in,
                                                 ushort* __restrict__ out, int n8)
{
    const int i = blockIdx.x * 256 + threadIdx.x;
    if (i >= n8) return;
    const float4 a = ((const float4*)in)[2 * i];
    const float4 b = ((const float4*)in)[2 * i + 1];
    ushort u[8] = {f2bf(a.x), f2bf(a.y), f2bf(a.z), f2bf(a.w),
                   f2bf(b.x), f2bf(b.y), f2bf(b.z), f2bf(b.w)};
    ((uint4*)out)[i] = *(uint4*)u;
}

// ------------------- transpose-cast: f32 [R,C] -> bf16 [C,R] ----------------
__global__ __launch_bounds__(256) void tcast(const float* __restrict__ in,
                                             ushort* __restrict__ out,
                                             int R, int C)
{
    __shared__ float tile[64][68];
    const int t  = threadIdx.x;
    const int c0 = blockIdx.x * 64, r0 = blockIdx.y * 64;
    const int lr = t >> 2, lc = (t & 3) * 16;
#pragma unroll
    for (int j = 0; j < 4; ++j) {
        const float4 v = *(const float4*)&in[(size_t)(r0 + lr) * C + c0 + lc + 4 * j];
        *(float4*)&tile[lr][lc + 4 * j] = v;
    }
    __syncthreads();
    const int oc = t >> 2, och = (t & 3) * 16;
    uint u[8];
#pragma unroll
    for (int j = 0; j < 8; ++j) {
        const float f0 = tile[och + 2 * j][oc];
        const float f1 = tile[och + 2 * j + 1][oc];
        u[j] = (uint)f2bf(f0) | ((uint)f2bf(f1) << 16);
    }
    uint4* dst = (uint4*)&out[(size_t)(c0 + oc) * R + r0 + och];
    dst[0] = make_uint4(u[0], u[1], u[2], u[3]);
    dst[1] = make_uint4(u[4], u[5], u[6], u[7]);
}

// --------------- bf16 MFMA GEMM: C[M,N]f32 = A[M,K] @ Bt[N,K]^T -------------
// 128x128 tile, BK=64, 4 waves (2x2), wave-tile 64x64 = 4x4 mfma 16x16x32.
// LDS XOR-swizzle (T2): byte ^= (row&7)<<4.  z picks one of 2 (A,B,C) triples.
__global__ __launch_bounds__(256) void gemm_bf16(
    const ushort* __restrict__ A0, const ushort* __restrict__ A1,
    const ushort* __restrict__ B0, const ushort* __restrict__ B1,
    float* __restrict__ C0, float* __restrict__ C1,
    int M, int N, int K)
{
    const int z = blockIdx.z;
    const ushort* A = z ? A1 : A0;
    const ushort* B = z ? B1 : B0;
    float* C       = z ? C1 : C0;

    __shared__ ushort As[128 * 64];
    __shared__ ushort Bs[128 * 64];

    const int tid  = threadIdx.x;
    const int lane = tid & 63;
    const int wave = tid >> 6;
    const int wm = wave >> 1, wn = wave & 1;
    const int bm = blockIdx.x * 128, bn = blockIdx.y * 128;

    const int srow  = tid >> 1;      // staging row 0..127
    const int spart = tid & 1;

    const int ml = lane & 15;        // fragment row within 16x16
    const int g  = lane >> 4;        // k-group 0..3

    f32x4 acc[4][4];
#pragma unroll
    for (int i = 0; i < 4; ++i)
#pragma unroll
        for (int j = 0; j < 4; ++j) acc[i][j] = (f32x4){0.f, 0.f, 0.f, 0.f};

    const size_t arow_off = (size_t)(bm + srow) * K;
    const size_t brow_off = (size_t)(bn + srow) * K;

    for (int k0 = 0; k0 < K; k0 += 64) {
#pragma unroll
        for (int j = 0; j < 4; ++j) {
            const int ch = spart * 4 + j;  // 16B chunk 0..7 within the 128B row
            const int sw = ((srow * 128 + ch * 16) ^ ((srow & 7) << 4)) >> 1;
            *(uint4*)&As[sw] = *(const uint4*)&A[arow_off + k0 + ch * 8];
            *(uint4*)&Bs[sw] = *(const uint4*)&B[brow_off + k0 + ch * 8];
        }
        __syncthreads();
#pragma unroll
        for (int kk = 0; kk < 2; ++kk) {
            short8 af[4], bfr[4];
#pragma unroll
            for (int mi = 0; mi < 4; ++mi) {
                const int row = wm * 64 + mi * 16 + ml;
                const int sw  = ((row * 128 + (kk * 4 + g) * 16) ^ ((ml & 7) << 4)) >> 1;
                af[mi] = *(const short8*)&As[sw];
            }
#pragma unroll
            for (int ni = 0; ni < 4; ++ni) {
                const int row = wn * 64 + ni * 16 + ml;
                const int sw  = ((row * 128 + (kk * 4 + g) * 16) ^ ((ml & 7) << 4)) >> 1;
                bfr[ni] = *(const short8*)&Bs[sw];
            }
#pragma unroll
            for (int mi = 0; mi < 4; ++mi)
#pragma unroll
                for (int ni = 0; ni < 4; ++ni)
                    acc[mi][ni] = __builtin_amdgcn_mfma_f32_16x16x32_bf16(
                        af[mi], bfr[ni], acc[mi][ni], 0, 0, 0);
        }
        __syncthreads();
    }

    // epilogue: C/D layout col=lane&15, row=(lane>>4)*4+reg  [m89-verified]
#pragma unroll
    for (int mi = 0; mi < 4; ++mi)
#pragma unroll
        for (int ni = 0; ni < 4; ++ni) {
            const int col = bn + wn * 64 + ni * 16 + ml;
#pragma unroll
            for (int r = 0; r < 4; ++r) {
                const int row = bm + wm * 64 + mi * 16 + g * 4 + r;
                C[(size_t)row * N + col] = acc[mi][ni][r];
            }
        }
}

// ---------------- tiled f32 GEMM (kept for the g/gate path) -----------------
__global__ __launch_bounds__(256) void gemm_tile(
    const float* __restrict__ A0, const float* __restrict__ A1, const float* __restrict__ A2,
    const float* __restrict__ B0, const float* __restrict__ B1, const float* __restrict__ B2,
    float* __restrict__ C0, float* __restrict__ C1, float* __restrict__ C2,
    int M, int N, int Kd)
{
    const int z = blockIdx.z;
    const float* A = (z == 0) ? A0 : (z == 1) ? A1 : A2;
    const float* B = (z == 0) ? B0 : (z == 1) ? B1 : B2;
    float* C       = (z == 0) ? C0 : (z == 1) ? C1 : C2;

    __shared__ float As[8][128];
    __shared__ float Bs[8][128];

    const int tid  = threadIdx.x;
    const int bm   = blockIdx.x * 128;
    const int bn   = blockIdx.y * 128;
    const int arow = tid >> 1;
    const int acol = (tid & 1) << 2;
    const int brow = tid >> 5;
    const int bcol = (tid & 31) << 2;
    const int ty   = tid >> 4;
    const int tx   = tid & 15;

    float acc[8][8];
#pragma unroll
    for (int i = 0; i < 8; ++i)
#pragma unroll
        for (int j = 0; j < 8; ++j) acc[i][j] = 0.f;

    const float* Ap = A + (size_t)(bm + arow) * Kd + acol;
    const float* Bp = B + (size_t)brow * N + (bn + bcol);

    for (int k0 = 0; k0 < Kd; k0 += 8) {
        float4 av = *(const float4*)(Ap + k0);
        float4 bv = *(const float4*)(Bp + (size_t)k0 * N);
        As[acol + 0][arow] = av.x;
        As[acol + 1][arow] = av.y;
        As[acol + 2][arow] = av.z;
        As[acol + 3][arow] = av.w;
        *(float4*)&Bs[brow][bcol] = bv;
        __syncthreads();
#pragma unroll
        for (int k = 0; k < 8; ++k) {
            float4 a0 = *(const float4*)&As[k][ty * 4];
            float4 a1 = *(const float4*)&As[k][64 + ty * 4];
            float4 b0 = *(const float4*)&Bs[k][tx * 4];
            float4 b1 = *(const float4*)&Bs[k][64 + tx * 4];
            float aa[8] = {a0.x, a0.y, a0.z, a0.w, a1.x, a1.y, a1.z, a1.w};
            float bb[8] = {b0.x, b0.y, b0.z, b0.w, b1.x, b1.y, b1.z, b1.w};
#pragma unroll
            for (int i = 0; i < 8; ++i)
#pragma unroll
                for (int j = 0; j < 8; ++j)
                    acc[i][j] = fmaf(aa[i], bb[j], acc[i][j]);
        }
        __syncthreads();
    }

#pragma unroll
    for (int i = 0; i < 8; ++i) {
        int r = bm + ((i >> 2) << 6) + ty * 4 + (i & 3);
#pragma unroll
        for (int jg = 0; jg < 2; ++jg) {
            int c = bn + (jg << 6) + tx * 4;
            float4 v = make_float4(acc[i][jg * 4 + 0], acc[i][jg * 4 + 1],
                                   acc[i][jg * 4 + 2], acc[i][jg * 4 + 3]);
            *(float4*)(C + (size_t)r * N + c) = v;
        }
    }
}

// ------------------- small-N GEMM for beta: N = 16 -------------------------
__global__ __launch_bounds__(256) void gemm_n16(
    const float* __restrict__ A, const float* __restrict__ B,
    float* __restrict__ C, int M, int Kd)
{
    const int tid  = threadIdx.x;
    const int n    = tid & 15;
    const int mloc = tid >> 4;
    const int m    = blockIdx.x * 16 + mloc;
    const float* a  = A + (size_t)m * Kd;
    const float* bn = B + n;
    float acc = 0.f;
#pragma unroll 4
    for (int k0 = 0; k0 < Kd; k0 += 8) {
        float4 a0 = *(const float4*)(a + k0);
        float4 a1 = *(const float4*)(a + k0 + 4);
        acc = fmaf(a0.x, bn[(size_t)(k0 + 0) * 16], acc);
        acc = fmaf(a0.y, bn[(size_t)(k0 + 1) * 16], acc);
        acc = fmaf(a0.z, bn[(size_t)(k0 + 2) * 16], acc);
        acc = fmaf(a0.w, bn[(size_t)(k0 + 3) * 16], acc);
        acc = fmaf(a1.x, bn[(size_t)(k0 + 4) * 16], acc);
        acc = fmaf(a1.y, bn[(size_t)(k0 + 5) * 16], acc);
        acc = fmaf(a1.z, bn[(size_t)(k0 + 6) * 16], acc);
        acc = fmaf(a1.w, bn[(size_t)(k0 + 7) * 16], acc);
    }
    C[(size_t)m * 16 + n] = acc;
}

// --------------- depthwise causal conv (K=4) + SiLU, in-place ---------------
__global__ __launch_bounds__(256) void conv_silu(
    float* __restrict__ q, float* __restrict__ k, float* __restrict__ v,
    const float* __restrict__ wq, const float* __restrict__ wk,
    const float* __restrict__ wv)
{
    constexpr int T = 2048, C = 2048;
    const int gid   = blockIdx.x * 256 + threadIdx.x;
    const int which = gid >> 12;
    const int rem   = gid & 4095;
    const int b     = rem >> 11;
    const int c     = rem & 2047;
    float* x        = (which == 0) ? q : (which == 1) ? k : v;
    const float* w  = (which == 0) ? wq : (which == 1) ? wk : wv;

    const float w0 = w[c * 4 + 0], w1 = w[c * 4 + 1];
    const float w2 = w[c * 4 + 2], w3 = w[c * 4 + 3];
    float* p = x + (size_t)b * T * C + c;
    float xm3 = 0.f, xm2 = 0.f, xm1 = 0.f;

    for (int t0 = 0; t0 < T; t0 += 16) {
        float xt[16], yo[16];
#pragma unroll
        for (int j = 0; j < 16; ++j) xt[j] = p[(size_t)(t0 + j) * C];
#pragma unroll
        for (int j = 0; j < 16; ++j) {
            float y = fmaf(xm3, w0, fmaf(xm2, w1, fmaf(xm1, w2, xt[j] * w3)));
            yo[j] = y / (1.f + __expf(-y));
            xm3 = xm2; xm2 = xm1; xm1 = xt[j];
        }
#pragma unroll
        for (int j = 0; j < 16; ++j) p[(size_t)(t0 + j) * C] = yo[j];
    }
}

// ------ prep: l2norm(q)*D^-0.5, l2norm(k), g -> exp(-exp(A_log)*softplus) ---
__global__ __launch_bounds__(256) void prep_qkg(
    float* __restrict__ Qb, float* __restrict__ Kb, float* __restrict__ Gb,
    const float* __restrict__ A_log, const float* __restrict__ dt_bias,
    int rows)
{
    const int wave = threadIdx.x >> 6;
    const int lane = threadIdx.x & 63;
    const int row  = blockIdx.x * 4 + wave;
    if (row >= rows) return;
    const int hh = row & 15;
    const size_t base = (size_t)row * 128;

    float q0 = Qb[base + lane], q1 = Qb[base + 64 + lane];
    float k0 = Kb[base + lane], k1 = Kb[base + 64 + lane];
    float sq = q0 * q0 + q1 * q1;
    float sk = k0 * k0 + k1 * k1;
#pragma unroll
    for (int off = 32; off >= 1; off >>= 1) {
        sq += __shfl_xor(sq, off);
        sk += __shfl_xor(sk, off);
    }
    const float qs = rsqrtf(sq + 1e-6f) * 0.08838834764831845f;
    const float ks = rsqrtf(sk + 1e-6f);
    Qb[base + lane] = q0 * qs; Qb[base + 64 + lane] = q1 * qs;
    Kb[base + lane] = k0 * ks; Kb[base + 64 + lane] = k1 * ks;

    const float a = __expf(A_log[hh]);
    float x0 = Gb[base + lane]      + dt_bias[hh * 128 + lane];
    float x1 = Gb[base + 64 + lane] + dt_bias[hh * 128 + 64 + lane];
    float sp0 = (x0 > 20.f) ? x0 : log1pf(__expf(x0));
    float sp1 = (x1 > 20.f) ? x1 : log1pf(__expf(x1));
    Gb[base + lane]      = __expf(-a * sp0);
    Gb[base + 64 + lane] = __expf(-a * sp1);
}

// --------------------- gated delta-rule sequential scan ---------------------
// 256 blocks = (vg 0..7) x (b,h 0..31); 1 wave; lane = (col 0..15, slice 0..3).
// s[32]/lane; kS/o by quad shuffles; k/eg/q in double-buffered LDS with
// per-slice chunk rotation (bank-conflict-free reads); 2-step prefetch.
__global__ __launch_bounds__(64) void kda_scan(
    const float* __restrict__ Q, const float* __restrict__ Kk,
    const float* __restrict__ V, const float* __restrict__ EG,
    const float* __restrict__ Braw, float* __restrict__ O)
{
    constexpr int T = 2048, H = 16, HD = 2048;
    const int bid = blockIdx.x;
    const int bh  = bid & 31;          // same (b,h) groups land on one XCD
    const int vg  = bid >> 5;
    const int b = bh >> 4, hh = bh & 15;
    const int lane = threadIdx.x;
    const int col  = lane >> 2;
    const int sl   = lane & 3;
    const int vcol = vg * 16 + col;

    __shared__ __align__(16) float kb_s[2][128];
    __shared__ __align__(16) float eb_s[2][128];
    __shared__ __align__(16) float qb_s[2][128];

    float s[32];
#pragma unroll
    for (int i = 0; i < 32; ++i) s[i] = 0.f;

    const size_t tok0 = (size_t)b * T;
    const int cb = hh * 128;
    const float* qp = Q  + tok0 * HD + cb;
    const float* kp = Kk + tok0 * HD + cb;
    const float* ep = EG + tok0 * HD + cb;
    const float* vp = V  + tok0 * HD + cb;
    const float* bp = Braw + tok0 * H + hh;
    float* op = O + tok0 * HD + cb;

    // storage position for this lane's staged float2 (chunk-rotated per slice)
    const int d0 = 2 * lane;
    const int sdv = d0 >> 5;
    const int cdv = (d0 >> 2) & 7;
    const int stpos = sdv * 32 + (((cdv + sdv) & 7) << 2) + (d0 & 3);

    // prologue: stage t=0, prefetch t=1
    {
        float2 k0v = *(const float2*)&kp[d0];
        float2 e0v = *(const float2*)&ep[d0];
        float2 q0v = *(const float2*)&qp[d0];
        *(float2*)&kb_s[0][stpos] = k0v;
        *(float2*)&eb_s[0][stpos] = e0v;
        *(float2*)&qb_s[0][stpos] = q0v;
    }
    float rv  = vp[vcol];
    float rb  = bp[0];
    float2 pk = *(const float2*)&kp[HD + d0];
    float2 pe = *(const float2*)&ep[HD + d0];
    float2 pq = *(const float2*)&qp[HD + d0];
    float rv1 = vp[HD + vcol];
    float rb1 = bp[H];

    for (int t = 0; t < T; ++t) {
        const int cur = t & 1, nxt = cur ^ 1;
        if (t + 1 < T) {                    // write staged t+1 (early)
            *(float2*)&kb_s[nxt][stpos] = pk;
            *(float2*)&eb_s[nxt][stpos] = pe;
            *(float2*)&qb_s[nxt][stpos] = pq;
        }
        float2 nk{}, ne{}, nq{}; float nv = 0.f, nb = 0.f;
        if (t + 2 < T) {                    // prefetch t+2
            const size_t o2 = (size_t)(t + 2) * HD;
            nk = *(const float2*)&kp[o2 + d0];
            ne = *(const float2*)&ep[o2 + d0];
            nq = *(const float2*)&qp[o2 + d0];
            nv = vp[o2 + vcol];
            nb = bp[(size_t)(t + 2) * H];
        }
        const float beta = 1.f / (1.f + __expf(-rb));

        // pass 1: decay + in-slice k.s
        float4 kreg[8];
        float a0 = 0.f, a1 = 0.f, a2 = 0.f, a3 = 0.f;
#pragma unroll
        for (int j = 0; j < 8; ++j) {
            const int ad = sl * 32 + (((j + sl) & 7) << 2);
            const float4 e4 = *(const float4*)&eb_s[cur][ad];
            const float4 k4 = *(const float4*)&kb_s[cur][ad];
            kreg[j] = k4;
            float s0 = s[4 * j + 0] * e4.x, s1 = s[4 * j + 1] * e4.y;
            float s2 = s[4 * j + 2] * e4.z, s3 = s[4 * j + 3] * e4.w;
            s[4 * j + 0] = s0; s[4 * j + 1] = s1;
            s[4 * j + 2] = s2; s[4 * j + 3] = s3;
            a0 = fmaf(k4.x, s0, a0); a1 = fmaf(k4.y, s1, a1);
            a2 = fmaf(k4.z, s2, a2); a3 = fmaf(k4.w, s3, a3);
        }
        float kS = (a0 + a1) + (a2 + a3);
        kS += __shfl_xor(kS, 1);
        kS += __shfl_xor(kS, 2);
        const float delta = beta * (rv - kS);

        // pass 2: rank-1 update + in-slice q.s
        float o0 = 0.f, o1 = 0.f, o2v = 0.f, o3 = 0.f;
#pragma unroll
        for (int j = 0; j < 8; ++j) {
            const int ad = sl * 32 + (((j + sl) & 7) << 2);
            const float4 q4 = *(const float4*)&qb_s[cur][ad];
            const float4 k4 = kreg[j];
            float s0 = fmaf(k4.x, delta, s[4 * j + 0]);
            float s1 = fmaf(k4.y, delta, s[4 * j + 1]);
            float s2 = fmaf(k4.z, delta, s[4 * j + 2]);
            float s3 = fmaf(k4.w, delta, s[4 * j + 3]);
            s[4 * j + 0] = s0; s[4 * j + 1] = s1;
            s[4 * j + 2] = s2; s[4 * j + 3] = s3;
            o0 = fmaf(q4.x, s0, o0); o1 = fmaf(q4.y, s1, o1);
            o2v = fmaf(q4.z, s2, o2v); o3 = fmaf(q4.w, s3, o3);
        }
        float oo = (o0 + o1) + (o2v + o3);
        oo += __shfl_xor(oo, 1);
        oo += __shfl_xor(oo, 2);
        if (sl == 0) op[(size_t)t * HD + vcol] = oo;

        rv = rv1; rb = rb1; rv1 = nv; rb1 = nb;
        pk = nk; pe = ne; pq = nq;
    }
}

// --------------- gated RMSNorm: o = rms(o)*norm_w*sigmoid(gate) -------------
__global__ __launch_bounds__(256) void norm_gate(
    float* __restrict__ O, const float* __restrict__ Gate,
    const float* __restrict__ norm_w, int rows)
{
    const int wave = threadIdx.x >> 6;
    const int lane = threadIdx.x & 63;
    const int row  = blockIdx.x * 4 + wave;
    if (row >= rows) return;
    const size_t base = (size_t)row * 128;

    float o0 = O[base + lane], o1 = O[base + 64 + lane];
    float ss = o0 * o0 + o1 * o1;
#pragma unroll
    for (int off = 32; off >= 1; off >>= 1) ss += __shfl_xor(ss, off);
    const float scale = rsqrtf(ss * (1.f / 128.f) + 1e-6f);

    const float g0 = Gate[base + lane], g1 = Gate[base + 64 + lane];
    o0 = o0 * scale * norm_w[lane]      * (1.f / (1.f + __expf(-g0)));
    o1 = o1 * scale * norm_w[64 + lane] * (1.f / (1.f + __expf(-g1)));
    O[base + lane] = o0;
    O[base + 64 + lane] = o1;
}

// ---------------------------------------------------------------------------
extern "C" void kernel_launch(void* const* d_in, const int* in_sizes, int n_in,
                              void* d_out, int out_size, void* d_ws, size_t ws_size,
                              hipStream_t stream)
{
    const float* h    = (const float*)d_in[0];
    const float* Wq   = (const float*)d_in[1];
    const float* Wk   = (const float*)d_in[2];
    const float* Wv   = (const float*)d_in[3];
    const float* cwq  = (const float*)d_in[4];
    const float* cwk  = (const float*)d_in[5];
    const float* cwv  = (const float*)d_in[6];
    const float* A_log= (const float*)d_in[7];
    const float* dtb  = (const float*)d_in[8];
    const float* Wfa  = (const float*)d_in[9];
    const float* Wfb  = (const float*)d_in[10];
    const float* Wb   = (const float*)d_in[11];
    const float* Wga  = (const float*)d_in[12];
    const float* Wgb  = (const float*)d_in[13];
    const float* nw   = (const float*)d_in[14];
    const float* Wo   = (const float*)d_in[15];
    float* out = (float*)d_out;

    const int M = 4096, HID = 2048;
    const size_t big = (size_t)M * HID;        // 8M floats
    float* ws    = (float*)d_ws;
    float* qb    = ws;                         // also gateb after the scan
    float* kb    = qb + big;
    float* vb    = kb + big;
    float* gb    = vb + big;
    float* ob    = gb + big;
    float* tmpf  = ob + big;                   // 4096x128
    float* tmpg  = tmpf + (size_t)M * 128;
    float* betab = tmpg + (size_t)M * 128;     // 4096x16
    ushort* hb16 = (ushort*)(betab + (size_t)M * 16);  // 8M bf16; also obb16
    ushort* wT1  = hb16 + big;                 // 4M bf16 (2048x2048 transposed)
    ushort* wT2  = wT1 + (size_t)HID * HID;
    float* gateb = qb;
    ushort* obb16 = hb16;

    dim3 blk(256);

    // casts / transposes for the MFMA path
    cast_bf16<<<dim3(4096), blk, 0, stream>>>(h, hb16, (int)(big / 8));
    tcast<<<dim3(32, 32), blk, 0, stream>>>(Wq, wT1, HID, HID);
    tcast<<<dim3(32, 32), blk, 0, stream>>>(Wk, wT2, HID, HID);

    // q,k projections (MFMA)
    gemm_bf16<<<dim3(32, 16, 2), blk, 0, stream>>>(
        hb16, hb16, wT1, wT2, qb, kb, M, HID, HID);

    // v projection (reuse wT1), then Wo transpose into wT2
    tcast<<<dim3(32, 32), blk, 0, stream>>>(Wv, wT1, HID, HID);
    gemm_bf16<<<dim3(32, 16, 1), blk, 0, stream>>>(
        hb16, hb16, wT1, wT1, vb, vb, M, HID, HID);
    tcast<<<dim3(32, 32), blk, 0, stream>>>(Wo, wT2, HID, HID);

    // g path in f32: h@{Wfa,Wga}; tmpf@Wfb -> gb
    gemm_tile<<<dim3(32, 1, 2), blk, 0, stream>>>(
        h, h, h, Wfa, Wga, Wga, tmpf, tmpg, tmpg, M, 128, HID);
    gemm_tile<<<dim3(32, 16, 1), blk, 0, stream>>>(
        tmpf, tmpf, tmpf, Wfb, Wfb, Wfb, gb, gb, gb, M, HID, 128);

    gemm_n16<<<dim3(M / 16), blk, 0, stream>>>(h, Wb, betab, M, HID);
    conv_silu<<<dim3(48), blk, 0, stream>>>(qb, kb, vb, cwq, cwk, cwv);
    prep_qkg<<<dim3(16384), blk, 0, stream>>>(qb, kb, gb, A_log, dtb, M * 16);

    // gated delta-rule scan
    kda_scan<<<dim3(256), dim3(64), 0, stream>>>(qb, kb, vb, gb, betab, ob);

    // gate projection after the scan (qb is dead -> reuse as gateb)
    gemm_tile<<<dim3(32, 16, 1), blk, 0, stream>>>(
        tmpg, tmpg, tmpg, Wgb, Wgb, Wgb, gateb, gateb, gateb, M, HID, 128);
    norm_gate<<<dim3(16384), blk, 0, stream>>>(ob, gateb, nw, M * 16);

    // output projection (MFMA)
    cast_bf16<<<dim3(4096), blk, 0, stream>>>(ob, obb16, (int)(big / 8));
    gemm_bf16<<<dim3(32, 16, 1), blk, 0, stream>>>(
        obb16, obb16, wT2, wT2, out, out, M, HID, HID);
}

// Round 5
// 2018.342 us; speedup vs baseline: 4.2740x; 1.3029x over previous
//
#include <hip/hip_runtime.h>
#include <hip/hip_bf16.h>

// ---------------------------------------------------------------------------
// KimiDeltaAttention — round 5.
//  * scan v3: 512 blocks (16 vgroups x 32 bh), batched LDS reads (one latency
//    exposure/step), s[16]/lane, conflict-free chunk permutation c^(c>>2).
//  * g/gate: composed weights (Wfa@Wfb, Wga@Wgb) -> bf16 MFMA path.
//  * conv: 4 T-segments (192 blocks) + halo-save pre-pass (race-free).
// ---------------------------------------------------------------------------

using short8 = __attribute__((ext_vector_type(8))) short;
using f32x4  = __attribute__((ext_vector_type(4))) float;

static __device__ __forceinline__ ushort f2bf(float f) {
    __hip_bfloat16 h = __float2bfloat16(f);
    return *reinterpret_cast<ushort*>(&h);
}

// ----------------------- row-major f32 -> bf16 cast -------------------------
__global__ __launch_bounds__(256) void cast_bf16(const float* __restrict__ in,
                                                 ushort* __restrict__ out, int n8)
{
    const int i = blockIdx.x * 256 + threadIdx.x;
    if (i >= n8) return;
    const float4 a = ((const float4*)in)[2 * i];
    const float4 b = ((const float4*)in)[2 * i + 1];
    ushort u[8] = {f2bf(a.x), f2bf(a.y), f2bf(a.z), f2bf(a.w),
                   f2bf(b.x), f2bf(b.y), f2bf(b.z), f2bf(b.w)};
    ((uint4*)out)[i] = *(uint4*)u;
}

// ------------------- transpose-cast: f32 [R,C] -> bf16 [C,R] ----------------
__global__ __launch_bounds__(256) void tcast(const float* __restrict__ in,
                                             ushort* __restrict__ out,
                                             int R, int C)
{
    __shared__ float tile[64][68];
    const int t  = threadIdx.x;
    const int c0 = blockIdx.x * 64, r0 = blockIdx.y * 64;
    const int lr = t >> 2, lc = (t & 3) * 16;
#pragma unroll
    for (int j = 0; j < 4; ++j) {
        const float4 v = *(const float4*)&in[(size_t)(r0 + lr) * C + c0 + lc + 4 * j];
        *(float4*)&tile[lr][lc + 4 * j] = v;
    }
    __syncthreads();
    const int oc = t >> 2, och = (t & 3) * 16;
    uint u[8];
#pragma unroll
    for (int j = 0; j < 8; ++j) {
        const float f0 = tile[och + 2 * j][oc];
        const float f1 = tile[och + 2 * j + 1][oc];
        u[j] = (uint)f2bf(f0) | ((uint)f2bf(f1) << 16);
    }
    uint4* dst = (uint4*)&out[(size_t)(c0 + oc) * R + r0 + och];
    dst[0] = make_uint4(u[0], u[1], u[2], u[3]);
    dst[1] = make_uint4(u[4], u[5], u[6], u[7]);
}

// --------------- bf16 MFMA GEMM: C[M,N]f32 = A[M,K] @ Bt[N,K]^T -------------
__global__ __launch_bounds__(256) void gemm_bf16(
    const ushort* __restrict__ A0, const ushort* __restrict__ A1,
    const ushort* __restrict__ B0, const ushort* __restrict__ B1,
    float* __restrict__ C0, float* __restrict__ C1,
    int M, int N, int K)
{
    const int z = blockIdx.z;
    const ushort* A = z ? A1 : A0;
    const ushort* B = z ? B1 : B0;
    float* C       = z ? C1 : C0;

    __shared__ ushort As[128 * 64];
    __shared__ ushort Bs[128 * 64];

    const int tid  = threadIdx.x;
    const int lane = tid & 63;
    const int wave = tid >> 6;
    const int wm = wave >> 1, wn = wave & 1;
    const int bm = blockIdx.x * 128, bn = blockIdx.y * 128;

    const int srow  = tid >> 1;
    const int spart = tid & 1;

    const int ml = lane & 15;
    const int g  = lane >> 4;

    f32x4 acc[4][4];
#pragma unroll
    for (int i = 0; i < 4; ++i)
#pragma unroll
        for (int j = 0; j < 4; ++j) acc[i][j] = (f32x4){0.f, 0.f, 0.f, 0.f};

    const size_t arow_off = (size_t)(bm + srow) * K;
    const size_t brow_off = (size_t)(bn + srow) * K;

    for (int k0 = 0; k0 < K; k0 += 64) {
#pragma unroll
        for (int j = 0; j < 4; ++j) {
            const int ch = spart * 4 + j;
            const int sw = ((srow * 128 + ch * 16) ^ ((srow & 7) << 4)) >> 1;
            *(uint4*)&As[sw] = *(const uint4*)&A[arow_off + k0 + ch * 8];
            *(uint4*)&Bs[sw] = *(const uint4*)&B[brow_off + k0 + ch * 8];
        }
        __syncthreads();
#pragma unroll
        for (int kk = 0; kk < 2; ++kk) {
            short8 af[4], bfr[4];
#pragma unroll
            for (int mi = 0; mi < 4; ++mi) {
                const int row = wm * 64 + mi * 16 + ml;
                const int sw  = ((row * 128 + (kk * 4 + g) * 16) ^ ((ml & 7) << 4)) >> 1;
                af[mi] = *(const short8*)&As[sw];
            }
#pragma unroll
            for (int ni = 0; ni < 4; ++ni) {
                const int row = wn * 64 + ni * 16 + ml;
                const int sw  = ((row * 128 + (kk * 4 + g) * 16) ^ ((ml & 7) << 4)) >> 1;
                bfr[ni] = *(const short8*)&Bs[sw];
            }
#pragma unroll
            for (int mi = 0; mi < 4; ++mi)
#pragma unroll
                for (int ni = 0; ni < 4; ++ni)
                    acc[mi][ni] = __builtin_amdgcn_mfma_f32_16x16x32_bf16(
                        af[mi], bfr[ni], acc[mi][ni], 0, 0, 0);
        }
        __syncthreads();
    }

#pragma unroll
    for (int mi = 0; mi < 4; ++mi)
#pragma unroll
        for (int ni = 0; ni < 4; ++ni) {
            const int col = bn + wn * 64 + ni * 16 + ml;
#pragma unroll
            for (int r = 0; r < 4; ++r) {
                const int row = bm + wm * 64 + mi * 16 + g * 4 + r;
                C[(size_t)row * N + col] = acc[mi][ni][r];
            }
        }
}

// -------- tiled f32 GEMM (used for the small weight-compose GEMMs) ---------
__global__ __launch_bounds__(256) void gemm_tile(
    const float* __restrict__ A0, const float* __restrict__ A1, const float* __restrict__ A2,
    const float* __restrict__ B0, const float* __restrict__ B1, const float* __restrict__ B2,
    float* __restrict__ C0, float* __restrict__ C1, float* __restrict__ C2,
    int M, int N, int Kd)
{
    const int z = blockIdx.z;
    const float* A = (z == 0) ? A0 : (z == 1) ? A1 : A2;
    const float* B = (z == 0) ? B0 : (z == 1) ? B1 : B2;
    float* C       = (z == 0) ? C0 : (z == 1) ? C1 : C2;

    __shared__ float As[8][128];
    __shared__ float Bs[8][128];

    const int tid  = threadIdx.x;
    const int bm   = blockIdx.x * 128;
    const int bn   = blockIdx.y * 128;
    const int arow = tid >> 1;
    const int acol = (tid & 1) << 2;
    const int brow = tid >> 5;
    const int bcol = (tid & 31) << 2;
    const int ty   = tid >> 4;
    const int tx   = tid & 15;

    float acc[8][8];
#pragma unroll
    for (int i = 0; i < 8; ++i)
#pragma unroll
        for (int j = 0; j < 8; ++j) acc[i][j] = 0.f;

    const float* Ap = A + (size_t)(bm + arow) * Kd + acol;
    const float* Bp = B + (size_t)brow * N + (bn + bcol);

    for (int k0 = 0; k0 < Kd; k0 += 8) {
        float4 av = *(const float4*)(Ap + k0);
        float4 bv = *(const float4*)(Bp + (size_t)k0 * N);
        As[acol + 0][arow] = av.x;
        As[acol + 1][arow] = av.y;
        As[acol + 2][arow] = av.z;
        As[acol + 3][arow] = av.w;
        *(float4*)&Bs[brow][bcol] = bv;
        __syncthreads();
#pragma unroll
        for (int k = 0; k < 8; ++k) {
            float4 a0 = *(const float4*)&As[k][ty * 4];
            float4 a1 = *(const float4*)&As[k][64 + ty * 4];
            float4 b0 = *(const float4*)&Bs[k][tx * 4];
            float4 b1 = *(const float4*)&Bs[k][64 + tx * 4];
            float aa[8] = {a0.x, a0.y, a0.z, a0.w, a1.x, a1.y, a1.z, a1.w};
            float bb[8] = {b0.x, b0.y, b0.z, b0.w, b1.x, b1.y, b1.z, b1.w};
#pragma unroll
            for (int i = 0; i < 8; ++i)
#pragma unroll
                for (int j = 0; j < 8; ++j)
                    acc[i][j] = fmaf(aa[i], bb[j], acc[i][j]);
        }
        __syncthreads();
    }

#pragma unroll
    for (int i = 0; i < 8; ++i) {
        int r = bm + ((i >> 2) << 6) + ty * 4 + (i & 3);
#pragma unroll
        for (int jg = 0; jg < 2; ++jg) {
            int c = bn + (jg << 6) + tx * 4;
            float4 v = make_float4(acc[i][jg * 4 + 0], acc[i][jg * 4 + 1],
                                   acc[i][jg * 4 + 2], acc[i][jg * 4 + 3]);
            *(float4*)(C + (size_t)r * N + c) = v;
        }
    }
}

// ------------------- small-N GEMM for beta: N = 16 -------------------------
__global__ __launch_bounds__(256) void gemm_n16(
    const float* __restrict__ A, const float* __restrict__ B,
    float* __restrict__ C, int M, int Kd)
{
    const int tid  = threadIdx.x;
    const int n    = tid & 15;
    const int mloc = tid >> 4;
    const int m    = blockIdx.x * 16 + mloc;
    const float* a  = A + (size_t)m * Kd;
    const float* bn = B + n;
    float acc = 0.f;
#pragma unroll 4
    for (int k0 = 0; k0 < Kd; k0 += 8) {
        float4 a0 = *(const float4*)(a + k0);
        float4 a1 = *(const float4*)(a + k0 + 4);
        acc = fmaf(a0.x, bn[(size_t)(k0 + 0) * 16], acc);
        acc = fmaf(a0.y, bn[(size_t)(k0 + 1) * 16], acc);
        acc = fmaf(a0.z, bn[(size_t)(k0 + 2) * 16], acc);
        acc = fmaf(a0.w, bn[(size_t)(k0 + 3) * 16], acc);
        acc = fmaf(a1.x, bn[(size_t)(k0 + 4) * 16], acc);
        acc = fmaf(a1.y, bn[(size_t)(k0 + 5) * 16], acc);
        acc = fmaf(a1.z, bn[(size_t)(k0 + 6) * 16], acc);
        acc = fmaf(a1.w, bn[(size_t)(k0 + 7) * 16], acc);
    }
    C[(size_t)m * 16 + n] = acc;
}

// ---- halo save: pre-conv values at segment boundaries (race-free split) ----
__global__ __launch_bounds__(256) void halo_save(
    const float* __restrict__ q, const float* __restrict__ k,
    const float* __restrict__ v, float* __restrict__ hal)
{
    constexpr int T = 2048, C = 2048, SEG = 512;
    const int idx = blockIdx.x * 256 + threadIdx.x;   // < 9*12288
    const int cid = idx % 12288;
    const int sh  = idx / 12288;      // 0..8
    const int sg  = sh / 3 + 1;       // segment 1..3
    const int ho  = sh % 3;           // halo offset 0..2
    const int which = cid >> 12, rem = cid & 4095, b = rem >> 11, c = rem & 2047;
    const float* x = (which == 0) ? q : (which == 1) ? k : v;
    hal[idx] = x[(size_t)b * T * C + (size_t)(sg * SEG - 3 + ho) * C + c];
}

// ------- depthwise causal conv (K=4) + SiLU, in-place, 4 T-segments ---------
__global__ __launch_bounds__(256) void conv_silu(
    float* __restrict__ q, float* __restrict__ k, float* __restrict__ v,
    const float* __restrict__ wq, const float* __restrict__ wk,
    const float* __restrict__ wv, const float* __restrict__ hal)
{
    constexpr int T = 2048, C = 2048, SEG = 512;
    const int seg    = blockIdx.x & 3;
    const int colblk = blockIdx.x >> 2;            // 0..47
    const int cid    = colblk * 256 + threadIdx.x; // 0..12287
    const int which  = cid >> 12;
    const int rem    = cid & 4095;
    const int b      = rem >> 11;
    const int c      = rem & 2047;
    float* x        = (which == 0) ? q : (which == 1) ? k : v;
    const float* w  = (which == 0) ? wq : (which == 1) ? wk : wv;

    const float w0 = w[c * 4 + 0], w1 = w[c * 4 + 1];
    const float w2 = w[c * 4 + 2], w3 = w[c * 4 + 3];
    float* p = x + (size_t)b * T * C + c;
    float xm3, xm2, xm1;
    if (seg == 0) { xm3 = xm2 = xm1 = 0.f; }
    else {
        xm3 = hal[((seg - 1) * 3 + 0) * 12288 + cid];
        xm2 = hal[((seg - 1) * 3 + 1) * 12288 + cid];
        xm1 = hal[((seg - 1) * 3 + 2) * 12288 + cid];
    }

    const int t0s = seg * SEG;
    for (int t0 = t0s; t0 < t0s + SEG; t0 += 16) {
        float xt[16], yo[16];
#pragma unroll
        for (int j = 0; j < 16; ++j) xt[j] = p[(size_t)(t0 + j) * C];
#pragma unroll
        for (int j = 0; j < 16; ++j) {
            float y = fmaf(xm3, w0, fmaf(xm2, w1, fmaf(xm1, w2, xt[j] * w3)));
            yo[j] = y / (1.f + __expf(-y));
            xm3 = xm2; xm2 = xm1; xm1 = xt[j];
        }
#pragma unroll
        for (int j = 0; j < 16; ++j) p[(size_t)(t0 + j) * C] = yo[j];
    }
}

// ------ prep: l2norm(q)*D^-0.5, l2norm(k), g -> exp(-exp(A_log)*softplus) ---
__global__ __launch_bounds__(256) void prep_qkg(
    float* __restrict__ Qb, float* __restrict__ Kb, float* __restrict__ Gb,
    const float* __restrict__ A_log, const float* __restrict__ dt_bias,
    int rows)
{
    const int wave = threadIdx.x >> 6;
    const int lane = threadIdx.x & 63;
    const int row  = blockIdx.x * 4 + wave;
    if (row >= rows) return;
    const int hh = row & 15;
    const size_t base = (size_t)row * 128;

    float q0 = Qb[base + lane], q1 = Qb[base + 64 + lane];
    float k0 = Kb[base + lane], k1 = Kb[base + 64 + lane];
    float sq = q0 * q0 + q1 * q1;
    float sk = k0 * k0 + k1 * k1;
#pragma unroll
    for (int off = 32; off >= 1; off >>= 1) {
        sq += __shfl_xor(sq, off);
        sk += __shfl_xor(sk, off);
    }
    const float qs = rsqrtf(sq + 1e-6f) * 0.08838834764831845f;
    const float ks = rsqrtf(sk + 1e-6f);
    Qb[base + lane] = q0 * qs; Qb[base + 64 + lane] = q1 * qs;
    Kb[base + lane] = k0 * ks; Kb[base + 64 + lane] = k1 * ks;

    const float a = __expf(A_log[hh]);
    float x0 = Gb[base + lane]      + dt_bias[hh * 128 + lane];
    float x1 = Gb[base + 64 + lane] + dt_bias[hh * 128 + 64 + lane];
    float sp0 = (x0 > 20.f) ? x0 : log1pf(__expf(x0));
    float sp1 = (x1 > 20.f) ? x1 : log1pf(__expf(x1));
    Gb[base + lane]      = __expf(-a * sp0);
    Gb[base + 64 + lane] = __expf(-a * sp1);
}

// --------------------- gated delta-rule sequential scan ---------------------
// 512 blocks = (vg 0..15) x (b,h 0..31); 1 wave; lane = (col 0..7, sl 0..7).
// s[16]/lane; batched ds_read_b128 (single latency exposure per step);
// chunk permutation p(c)=c^(c>>2) -> conflict-free; 3-shuffle reductions.
__global__ __launch_bounds__(64) void kda_scan(
    const float* __restrict__ Q, const float* __restrict__ Kk,
    const float* __restrict__ V, const float* __restrict__ EG,
    const float* __restrict__ Braw, float* __restrict__ O)
{
    constexpr int T = 2048, H = 16, HD = 2048;
    const int bid = blockIdx.x;
    const int bh  = bid & 31;          // bid%8==bh%8 -> vgroups of one (b,h) share an XCD
    const int vg  = bid >> 5;          // 0..15
    const int b = bh >> 4, hh = bh & 15;
    const int lane = threadIdx.x;
    const int col  = lane >> 3;        // 0..7
    const int sl   = lane & 7;         // 0..7 (k-slice)
    const int vcol = vg * 8 + col;

    __shared__ __align__(16) float kb_s[2][128];
    __shared__ __align__(16) float eb_s[2][128];
    __shared__ __align__(16) float qb_s[2][128];

    float s[16];
#pragma unroll
    for (int i = 0; i < 16; ++i) s[i] = 0.f;

    const size_t tok0 = (size_t)b * T;
    const int cb = hh * 128;
    const float* qp = Q  + tok0 * HD + cb;
    const float* kp = Kk + tok0 * HD + cb;
    const float* ep = EG + tok0 * HD + cb;
    const float* vp = V  + tok0 * HD + cb;
    const float* bp = Braw + tok0 * H + hh;
    float* op = O + tok0 * HD + cb;

    // write position: lane stages float2 covering chunk cw = lane>>1,
    // stored at permuted chunk pw = cw ^ (cw>>2)
    const int d0 = 2 * lane;
    const int cw = lane >> 1;
    const int pw = cw ^ (cw >> 2);
    const int stpos = pw * 4 + (d0 & 3);

    // read offsets: chunk c = 4*sl+j stored at (c ^ sl)  (c>>2 == sl)
    int rof[4];
#pragma unroll
    for (int j = 0; j < 4; ++j) rof[j] = (((sl << 2) + j) ^ sl) << 2;

    // prologue: stage t=0, prefetch t=1
    *(float2*)&kb_s[0][stpos] = *(const float2*)&kp[d0];
    *(float2*)&eb_s[0][stpos] = *(const float2*)&ep[d0];
    *(float2*)&qb_s[0][stpos] = *(const float2*)&qp[d0];
    float rv  = vp[vcol];
    float rb  = bp[0];
    float2 pk = *(const float2*)&kp[HD + d0];
    float2 pe = *(const float2*)&ep[HD + d0];
    float2 pq = *(const float2*)&qp[HD + d0];
    float rv1 = vp[HD + vcol];
    float rb1 = bp[H];

    for (int t = 0; t < T; ++t) {
        const int cur = t & 1, nxt = cur ^ 1;
        if (t + 1 < T) {                    // write staged t+1 (other buffer)
            *(float2*)&kb_s[nxt][stpos] = pk;
            *(float2*)&eb_s[nxt][stpos] = pe;
            *(float2*)&qb_s[nxt][stpos] = pq;
        }
        float2 nk{}, ne{}, nq{}; float nv = 0.f, nb = 0.f;
        if (t + 2 < T) {                    // prefetch t+2
            const size_t o2 = (size_t)(t + 2) * HD;
            nk = *(const float2*)&kp[o2 + d0];
            ne = *(const float2*)&ep[o2 + d0];
            nq = *(const float2*)&qp[o2 + d0];
            nv = vp[o2 + vcol];
            nb = bp[(size_t)(t + 2) * H];
        }
        const float beta = 1.f / (1.f + __expf(-rb));

        // batched LDS reads: one latency exposure for all 12 b128 reads
        float4 er[4], kr[4], qr[4];
#pragma unroll
        for (int j = 0; j < 4; ++j) {
            er[j] = *(const float4*)&eb_s[cur][rof[j]];
            kr[j] = *(const float4*)&kb_s[cur][rof[j]];
            qr[j] = *(const float4*)&qb_s[cur][rof[j]];
        }

        // pass 1: decay + in-slice k.s
        float a0 = 0.f, a1 = 0.f, a2 = 0.f, a3 = 0.f;
#pragma unroll
        for (int j = 0; j < 4; ++j) {
            float s0 = s[4 * j + 0] * er[j].x, s1 = s[4 * j + 1] * er[j].y;
            float s2 = s[4 * j + 2] * er[j].z, s3 = s[4 * j + 3] * er[j].w;
            s[4 * j + 0] = s0; s[4 * j + 1] = s1;
            s[4 * j + 2] = s2; s[4 * j + 3] = s3;
            a0 = fmaf(kr[j].x, s0, a0); a1 = fmaf(kr[j].y, s1, a1);
            a2 = fmaf(kr[j].z, s2, a2); a3 = fmaf(kr[j].w, s3, a3);
        }
        float kS = (a0 + a1) + (a2 + a3);
        kS += __shfl_xor(kS, 1);
        kS += __shfl_xor(kS, 2);
        kS += __shfl_xor(kS, 4);
        const float delta = beta * (rv - kS);

        // pass 2: rank-1 update + in-slice q.s
        float o0 = 0.f, o1 = 0.f, o2v = 0.f, o3 = 0.f;
#pragma unroll
        for (int j = 0; j < 4; ++j) {
            float s0 = fmaf(kr[j].x, delta, s[4 * j + 0]);
            float s1 = fmaf(kr[j].y, delta, s[4 * j + 1]);
            float s2 = fmaf(kr[j].z, delta, s[4 * j + 2]);
            float s3 = fmaf(kr[j].w, delta, s[4 * j + 3]);
            s[4 * j + 0] = s0; s[4 * j + 1] = s1;
            s[4 * j + 2] = s2; s[4 * j + 3] = s3;
            o0 = fmaf(qr[j].x, s0, o0); o1 = fmaf(qr[j].y, s1, o1);
            o2v = fmaf(qr[j].z, s2, o2v); o3 = fmaf(qr[j].w, s3, o3);
        }
        float oo = (o0 + o1) + (o2v + o3);
        oo += __shfl_xor(oo, 1);
        oo += __shfl_xor(oo, 2);
        oo += __shfl_xor(oo, 4);
        if (sl == 0) op[(size_t)t * HD + vcol] = oo;

        rv = rv1; rb = rb1; rv1 = nv; rb1 = nb;
        pk = nk; pe = ne; pq = nq;
    }
}

// --------------- gated RMSNorm: o = rms(o)*norm_w*sigmoid(gate) -------------
__global__ __launch_bounds__(256) void norm_gate(
    float* __restrict__ O, const float* __restrict__ Gate,
    const float* __restrict__ norm_w, int rows)
{
    const int wave = threadIdx.x >> 6;
    const int lane = threadIdx.x & 63;
    const int row  = blockIdx.x * 4 + wave;
    if (row >= rows) return;
    const size_t base = (size_t)row * 128;

    float o0 = O[base + lane], o1 = O[base + 64 + lane];
    float ss = o0 * o0 + o1 * o1;
#pragma unroll
    for (int off = 32; off >= 1; off >>= 1) ss += __shfl_xor(ss, off);
    const float scale = rsqrtf(ss * (1.f / 128.f) + 1e-6f);

    const float g0 = Gate[base + lane], g1 = Gate[base + 64 + lane];
    o0 = o0 * scale * norm_w[lane]      * (1.f / (1.f + __expf(-g0)));
    o1 = o1 * scale * norm_w[64 + lane] * (1.f / (1.f + __expf(-g1)));
    O[base + lane] = o0;
    O[base + 64 + lane] = o1;
}

// ---------------------------------------------------------------------------
extern "C" void kernel_launch(void* const* d_in, const int* in_sizes, int n_in,
                              void* d_out, int out_size, void* d_ws, size_t ws_size,
                              hipStream_t stream)
{
    const float* h    = (const float*)d_in[0];
    const float* Wq   = (const float*)d_in[1];
    const float* Wk   = (const float*)d_in[2];
    const float* Wv   = (const float*)d_in[3];
    const float* cwq  = (const float*)d_in[4];
    const float* cwk  = (const float*)d_in[5];
    const float* cwv  = (const float*)d_in[6];
    const float* A_log= (const float*)d_in[7];
    const float* dtb  = (const float*)d_in[8];
    const float* Wfa  = (const float*)d_in[9];
    const float* Wfb  = (const float*)d_in[10];
    const float* Wb   = (const float*)d_in[11];
    const float* Wga  = (const float*)d_in[12];
    const float* Wgb  = (const float*)d_in[13];
    const float* nw   = (const float*)d_in[14];
    const float* Wo   = (const float*)d_in[15];
    float* out = (float*)d_out;

    const int M = 4096, HID = 2048;
    const size_t big = (size_t)M * HID;        // 8M elements
    float* ws    = (float*)d_ws;
    float* qb    = ws;          // post-scan: gateb
    float* kb    = qb + big;    // post-scan: Wgcomb f32 scratch
    float* vb    = kb + big;    // post-scan: obb16 (bf16) scratch
    float* gb    = vb + big;
    float* ob    = gb + big;    // pre-scan: Wcomb f32 scratch
    float* betab = ob + big;                        // 4096x16
    float* halb  = betab + (size_t)M * 16;          // 9*12288 halo floats
    ushort* hb16 = (ushort*)(halb + 110592);        // [M,HID] bf16
    ushort* wT1  = hb16 + big;                      // [2048,2048] bf16
    ushort* wT2  = wT1 + (size_t)HID * HID;

    float* gateb   = qb;
    float* wgcombf = kb;
    ushort* obb16  = (ushort*)vb;
    float* wcombf  = ob;

    dim3 blk(256);

    // h -> bf16; Wq/Wk transposed-cast
    cast_bf16<<<dim3(4096), blk, 0, stream>>>(h, hb16, (int)(big / 8));
    tcast<<<dim3(32, 32), blk, 0, stream>>>(Wq, wT1, HID, HID);
    tcast<<<dim3(32, 32), blk, 0, stream>>>(Wk, wT2, HID, HID);

    // q,k projections (MFMA)
    gemm_bf16<<<dim3(32, 16, 2), blk, 0, stream>>>(
        hb16, hb16, wT1, wT2, qb, kb, M, HID, HID);

    // compose Wcomb = Wfa@Wfb (f32, 2048x2048, K=128) into ob scratch
    gemm_tile<<<dim3(16, 16, 1), blk, 0, stream>>>(
        Wfa, Wfa, Wfa, Wfb, Wfb, Wfb, wcombf, wcombf, wcombf, HID, HID, 128);
    tcast<<<dim3(32, 32), blk, 0, stream>>>(Wv, wT1, HID, HID);
    tcast<<<dim3(32, 32), blk, 0, stream>>>(wcombf, wT2, HID, HID);

    // v, g projections (MFMA)
    gemm_bf16<<<dim3(32, 16, 2), blk, 0, stream>>>(
        hb16, hb16, wT1, wT2, vb, gb, M, HID, HID);

    // beta
    gemm_n16<<<dim3(M / 16), blk, 0, stream>>>(h, Wb, betab, M, HID);

    // conv + SiLU (segmented, race-free via halo snapshot)
    halo_save<<<dim3(432), blk, 0, stream>>>(qb, kb, vb, halb);
    conv_silu<<<dim3(192), blk, 0, stream>>>(qb, kb, vb, cwq, cwk, cwv, halb);

    // l2norm q/k, g -> exp(g)
    prep_qkg<<<dim3(16384), blk, 0, stream>>>(qb, kb, gb, A_log, dtb, M * 16);

    // gated delta-rule scan
    kda_scan<<<dim3(512), dim3(64), 0, stream>>>(qb, kb, vb, gb, betab, ob);

    // gate path: compose Wga@Wgb (f32) -> bf16 -> MFMA into gateb(=qb)
    gemm_tile<<<dim3(16, 16, 1), blk, 0, stream>>>(
        Wga, Wga, Wga, Wgb, Wgb, Wgb, wgcombf, wgcombf, wgcombf, HID, HID, 128);
    tcast<<<dim3(32, 32), blk, 0, stream>>>(wgcombf, wT1, HID, HID);
    gemm_bf16<<<dim3(32, 16, 1), blk, 0, stream>>>(
        hb16, hb16, wT1, wT1, gateb, gateb, M, HID, HID);

    // gated RMSNorm
    norm_gate<<<dim3(16384), blk, 0, stream>>>(ob, gateb, nw, M * 16);

    // output projection (MFMA)
    cast_bf16<<<dim3(4096), blk, 0, stream>>>(ob, obb16, (int)(big / 8));
    tcast<<<dim3(32, 32), blk, 0, stream>>>(Wo, wT2, HID, HID);
    gemm_bf16<<<dim3(32, 16, 1), blk, 0, stream>>>(
        obb16, obb16, wT2, wT2, out, out, M, HID, HID);
}